// Round 7
// baseline (402.444 us; speedup 1.0000x reference)
//
#include <hip/hip_runtime.h>
#include <cstdint>
#include <cstddef>

#define BB 32
#define NN 1024
#define CIN 128
#define FF 64
#define NOUT 10
#define CAP 128
#define EPSV 1e-5f

// non-temporal float4 load: stream-once data (A, x, Xin) must not evict gather-hot rows.
typedef float vf4 __attribute__((ext_vector_type(4)));
__device__ __forceinline__ float4 ldnt(const float4* p) {
    vf4 v = __builtin_nontemporal_load((const vf4*)p);
    return make_float4(v.x, v.y, v.z, v.w);
}

// ---------------- fused front: [0,8192) CSR, [8192,10240) x@W0 gemm, [10240] seed ----
// R3-proven, unchanged.
__global__ __launch_bounds__(256) void k_front(const float* __restrict__ A,
                                               const float* __restrict__ x,
                                               const float* __restrict__ W0,
                                               const int* __restrict__ Nn,
                                               const float* __restrict__ b2f,
                                               float* __restrict__ gmax,
                                               unsigned short* __restrict__ adj,
                                               int* __restrict__ cnt,
                                               float* __restrict__ c1,
                                               float* __restrict__ c2,
                                               float* __restrict__ T) {
    __shared__ __align__(16) float Wl[64 * 64];    // 16 KB
    int tid = threadIdx.x;
    int wave = tid >> 6, lane = tid & 63;
    if (blockIdx.x >= 10240) {
        for (int i = tid; i < BB * 64; i += 256)
            gmax[i] = fmaxf(b2f[i & 63], 0.f);     // exact relu(b2) seed (dead rows)
        return;
    }
    if (blockIdx.x >= 8192) {
        int gid = blockIdx.x - 8192;        // gid%8 == b%8: XCD matches spmm
        int b = gid & 31;
        int cch = gid >> 5;
        if (cch * 16 >= Nn[b]) return;
        int row0 = (b << 10) + cch * 16;
        int rsub = lane >> 4, f0 = (lane & 15) * 4;
        int r = row0 + wave * 4 + rsub;
        const float4* xr = (const float4*)(x + (size_t)r * CIN);
        float4 acc = {0.f, 0.f, 0.f, 0.f};
#pragma unroll
        for (int kc = 0; kc < 2; ++kc) {
            if (kc) __syncthreads();
            for (int t = tid; t < 64 * 16; t += 256)
                ((float4*)Wl)[t] = ((const float4*)W0)[kc * 1024 + t];
            __syncthreads();
#pragma unroll 4
            for (int k4 = 0; k4 < 16; ++k4) {
                float4 xv = ldnt(xr + kc * 16 + k4);
                float4 w0 = *(const float4*)&Wl[(k4 * 4 + 0) * 64 + f0];
                float4 w1 = *(const float4*)&Wl[(k4 * 4 + 1) * 64 + f0];
                float4 w2 = *(const float4*)&Wl[(k4 * 4 + 2) * 64 + f0];
                float4 w3 = *(const float4*)&Wl[(k4 * 4 + 3) * 64 + f0];
                acc.x += xv.x * w0.x; acc.y += xv.x * w0.y; acc.z += xv.x * w0.z; acc.w += xv.x * w0.w;
                acc.x += xv.y * w1.x; acc.y += xv.y * w1.y; acc.z += xv.y * w1.z; acc.w += xv.y * w1.w;
                acc.x += xv.z * w2.x; acc.y += xv.z * w2.y; acc.z += xv.z * w2.z; acc.w += xv.z * w2.w;
                acc.x += xv.w * w3.x; acc.y += xv.w * w3.y; acc.z += xv.w * w3.z; acc.w += xv.w * w3.w;
            }
        }
        *(float4*)&T[(size_t)r * 64 + f0] = acc;
    } else {
        int r = blockIdx.x * 4 + wave;
        int b = r >> 10;
        int Nb = Nn[b];
        int rl = r & 1023;
        if (rl >= Nb) {
            if (lane == 0) {
                cnt[r] = 0;
                float D = 1.0f / sqrtf(1.0f + EPSV);
                c1[r] = D;
                c2[r] = D * D;
            }
            return;
        }
        unsigned short* adjs = ((unsigned short*)Wl) + wave * CAP;
        const float4* Arow = (const float4*)(A + (size_t)r * NN);
        int nch = (Nb + 255) >> 8;
        float4 z4 = {0.f, 0.f, 0.f, 0.f};
        float4 v0 = ldnt(Arow + lane);
        float4 v1 = ldnt(Arow + 64 + lane);
        float4 v2 = (nch > 2) ? ldnt(Arow + 128 + lane) : z4;
        float4 v3 = (nch > 3) ? ldnt(Arow + 192 + lane) : z4;
        int c = 0;
        unsigned long long lt = (lane == 0) ? 0ULL : ((1ULL << lane) - 1ULL);
        float4 vv[4] = {v0, v1, v2, v3};
#pragma unroll
        for (int it = 0; it < 4; ++it) {
            float4 v = vv[it];
            int j0 = it * 256 + lane * 4;
            unsigned long long m0 = __ballot(v.x != 0.f);
            unsigned long long m1 = __ballot(v.y != 0.f);
            unsigned long long m2 = __ballot(v.z != 0.f);
            unsigned long long m3 = __ballot(v.w != 0.f);
            int before = __popcll(m0 & lt) + __popcll(m1 & lt) +
                         __popcll(m2 & lt) + __popcll(m3 & lt);
            int p = c + before;
            if (v.x != 0.f) { if (p < CAP) adjs[p] = (unsigned short)(j0 + 0); ++p; }
            if (v.y != 0.f) { if (p < CAP) adjs[p] = (unsigned short)(j0 + 1); ++p; }
            if (v.z != 0.f) { if (p < CAP) adjs[p] = (unsigned short)(j0 + 2); ++p; }
            if (v.w != 0.f) { if (p < CAP) adjs[p] = (unsigned short)(j0 + 3); ++p; }
            c += __popcll(m0) + __popcll(m1) + __popcll(m2) + __popcll(m3);
        }
        int cc = (c > CAP) ? CAP : c;
        uint32_t* dst = (uint32_t*)(adj + (size_t)r * CAP);
        if (lane * 2 < cc) dst[lane] = ((const uint32_t*)adjs)[lane];
        if (lane == 0) {
            cnt[r] = cc;
            float D = 1.0f / sqrtf((float)c + 1.0f + EPSV);
            c1[r] = D;
            c2[r] = D * D;
        }
    }
}

// ---------------- SpMM (R3-proven body), templated on deferred scale --------------------
// DEFER=0 (layer 1): gather c1s[j]*T[j,l], self c2[r]*T[r,l] — byte-identical to R3.
// DEFER=1 (layers 2/3): T holds the RAW gemm X@W; scale applied at gather:
//   c1s[j]*(scss[j]*T[j,l]) and self c2[r]*(scss[rl]*T[r,l]).
// R2-verified bit-identical rounding sequence to the pre-scaled path (scss[j]*T is
// exactly the old T_mid store; dead rows scss=0 -> exact 0 either way).
template<int DEFER>
__global__ __launch_bounds__(256) void k_spmm(const unsigned short* __restrict__ adj,
                                              const int* __restrict__ cnt,
                                              const float* __restrict__ c1,
                                              const float* __restrict__ c2,
                                              const float* __restrict__ T,
                                              const float* __restrict__ bias,
                                              float* __restrict__ X,
                                              const float* __restrict__ p,
                                              float* __restrict__ y,
                                              float* __restrict__ gmax,
                                              const int* __restrict__ Nn,
                                              const float* __restrict__ scs) {
    __shared__ __align__(16) float c1s[NN];
    __shared__ __align__(16) float scss[DEFER ? NN : 4];
    __shared__ float red[4][64];
    int b   = blockIdx.x & 31;            // graph
    int cch = blockIdx.x >> 5;            // chunk in [0,64)
    int Nb = Nn[b];
    if (cch * 16 >= Nb) return;
    int tid = threadIdx.x;
    int n4 = (Nb + 3) >> 2;
    if (tid < n4) {
        ((float4*)c1s)[tid] = ((const float4*)(c1 + (b << 10)))[tid];
        if (DEFER)
            ((float4*)scss)[tid] = ((const float4*)(scs + (b << 10)))[tid];
    }
    __syncthreads();
    int wave = tid >> 6, lane = tid & 63;
    int r0 = (b << 10) + cch * 16 + wave * 4;
    const float* Tb = T + ((size_t)(b << 10) << 6);
    float bv = bias[lane];
    float pv = 0.f, ppinv = 0.f;
    if (p != nullptr) {
        pv = p[lane];
        float pp = pv * pv;
        for (int s = 32; s; s >>= 1) pp += __shfl_xor(pp, s, 64);
        ppinv = 1.0f / sqrtf(pp);
    }
    float vmax = 0.f;
#pragma unroll
    for (int rr = 0; rr < 4; ++rr) {
        int r = r0 + rr;
        int rl = r & 1023;
        if (rl >= Nb) break;
        if (DEFER && c1s[rl] == 0.f) continue;   // pool-dropped (wave-uniform)
        const unsigned short* arow = adj + (size_t)r * CAP;
        int n = cnt[r];
        float acc0 = 0.f, acc1 = 0.f, acc2 = 0.f, acc3 = 0.f;
        int t = 0;
        for (; t + 4 <= n; t += 4) {
            ushort4 j4 = *(const ushort4*)(arow + t);
            float t0 = Tb[((int)j4.x << 6) + lane];
            float t1 = Tb[((int)j4.y << 6) + lane];
            float t2 = Tb[((int)j4.z << 6) + lane];
            float t3 = Tb[((int)j4.w << 6) + lane];
            if (DEFER) {
                t0 *= scss[j4.x]; t1 *= scss[j4.y];
                t2 *= scss[j4.z]; t3 *= scss[j4.w];
            }
            acc0 += c1s[j4.x] * t0;
            acc1 += c1s[j4.y] * t1;
            acc2 += c1s[j4.z] * t2;
            acc3 += c1s[j4.w] * t3;
        }
        for (; t < n; ++t) {
            int j = arow[t];
            float tv = Tb[(j << 6) + lane];
            if (DEFER) tv *= scss[j];
            acc0 += c1s[j] * tv;
        }
        float acc = (acc0 + acc1) + (acc2 + acc3);
        float selfT = T[((size_t)r << 6) + lane];
        if (DEFER) selfT = scss[rl] * selfT;
        float o = c1s[rl] * acc + c2[r] * selfT + bv;
        o = fmaxf(o, 0.f);
        if (X != nullptr) X[((size_t)r << 6) + lane] = o;
        if (p != nullptr) {
            float a = o * pv;
            for (int s = 32; s; s >>= 1) a += __shfl_xor(a, s, 64);
            if (lane == 0) y[r] = a * ppinv;
        }
        vmax = fmaxf(vmax, o);
    }
    if (gmax != nullptr) {
        red[wave][lane] = vmax;
        __syncthreads();
        if (wave == 0) {
            float m = fmaxf(fmaxf(red[0][lane], red[1][lane]),
                            fmaxf(red[2][lane], red[3][lane]));
            atomicMax((int*)&gmax[(b << 6) + lane], __float_as_int(m));
        }
    }
}

// ---------------- fused rank+deg+coeffs [0,512) + RAW gemm64 [512,2560) ------------------
// Rank blocks (16/graph): R4-verified u64-key stable rank of all 1024 nodes (2 ops/pair)
// -> full nm in LDS -> masked degree (bit-exact: same lane-gather + butterfly as k_mid)
// + coefficients for its 64-row slice:
//   c1[r]=m*D, c2[r]=D*D, scs[r]=tanh(y)*m  (scs=0, c1=0 for dropped rows).
// Gemm blocks: k_mid's proven gemm64 body WITHOUT the row scale (raw X@W -> T).
// Both halves depend only on the previous spmm -> one dispatch replaces rank + mid.
__global__ __launch_bounds__(256) void k_rankgemm(const float* __restrict__ y,
                                                  const float* __restrict__ maskSrc,
                                                  const int* __restrict__ nsrc,
                                                  const int* __restrict__ Nn,
                                                  const unsigned short* __restrict__ adj,
                                                  const int* __restrict__ cnt,
                                                  const float* __restrict__ Xin,
                                                  const float* __restrict__ W,
                                                  float* __restrict__ nmOut,
                                                  int* __restrict__ ncur,
                                                  float* __restrict__ c1o,
                                                  float* __restrict__ c2o,
                                                  float* __restrict__ scso,
                                                  float* __restrict__ T) {
    __shared__ __align__(16) char smem[16384];     // union: Wl | yv+kv+nml
    int tid = threadIdx.x;
    if (blockIdx.x >= 512) {
        // ---- raw gemm64: T[r,f] = sum_k Xin[r,k]*W[k,f] (no scale) ----
        float* Wl = (float*)smem;
        int gid = blockIdx.x - 512;         // 512%8==0 -> XCD gid%8 == b%8
        int b = gid & 31;
        int cch = gid >> 5;
        if (cch * 16 >= Nn[b]) return;
        int row0 = (b << 10) + cch * 16;
        for (int t = tid; t < 64 * 16; t += 256)
            ((float4*)Wl)[t] = ((const float4*)W)[t];
        __syncthreads();
        int wave = tid >> 6, lane = tid & 63;
        int rsub = lane >> 4, f0 = (lane & 15) * 4;
        int r = row0 + wave * 4 + rsub;
        const float4* xr = (const float4*)(Xin + (size_t)r * 64);
        float4 acc = {0.f, 0.f, 0.f, 0.f};
#pragma unroll 4
        for (int k4 = 0; k4 < 16; ++k4) {
            float4 xv = ldnt(xr + k4);
            float4 w0 = *(const float4*)&Wl[(k4 * 4 + 0) * 64 + f0];
            float4 w1 = *(const float4*)&Wl[(k4 * 4 + 1) * 64 + f0];
            float4 w2 = *(const float4*)&Wl[(k4 * 4 + 2) * 64 + f0];
            float4 w3 = *(const float4*)&Wl[(k4 * 4 + 3) * 64 + f0];
            acc.x += xv.x * w0.x; acc.y += xv.x * w0.y; acc.z += xv.x * w0.z; acc.w += xv.x * w0.w;
            acc.x += xv.y * w1.x; acc.y += xv.y * w1.y; acc.z += xv.y * w1.z; acc.w += xv.y * w1.w;
            acc.x += xv.z * w2.x; acc.y += xv.z * w2.y; acc.z += xv.z * w2.z; acc.w += xv.z * w2.w;
            acc.x += xv.w * w3.x; acc.y += xv.w * w3.y; acc.z += xv.w * w3.z; acc.w += xv.w * w3.w;
        }
        *(float4*)&T[(size_t)r * 64 + f0] = acc;
    } else {
        // ---- rank + deg + coeffs ----
        float* yv = (float*)smem;                                  // 4 KB
        unsigned long long* kv = (unsigned long long*)(smem + 4096); // 8 KB
        float* nml = (float*)(smem + 12288);                       // 4 KB
        int b = blockIdx.x >> 4;
        int sub = blockIdx.x & 15;
        const float INF = __builtin_inff();
        int Nb = Nn[b];
        if ((sub << 6) >= Nb) return;      // slice fully dead; never read downstream
        {
            float4 v;
            if (tid * 4 < Nb) {
                v = ((const float4*)(y + (b << 10)))[tid];
                float4 m = ((const float4*)(maskSrc + (b << 10)))[tid];
                v.x = (m.x > 0.f) ? v.x : INF;
                v.y = (m.y > 0.f) ? v.y : INF;
                v.z = (m.z > 0.f) ? v.z : INF;
                v.w = (m.w > 0.f) ? v.w : INF;
            } else {
                v.x = INF; v.y = INF; v.z = INF; v.w = INF;
            }
            ((float4*)yv)[tid] = v;
        }
        int n = nsrc[b];
        const float RM = (float)(1.0 - 0.8);   // 0.2f, matches jax f32 semantics
        int nrem = (int)((float)n * RM);
        if (sub == 0 && tid == 0) ncur[b] = n - nrem;
        __syncthreads();
#pragma unroll
        for (int t = 0; t < 4; ++t) {          // monotone order keys, idx tie-break
            int i = tid + (t << 8);
            unsigned int u = __float_as_uint(yv[i]);
            u ^= (unsigned int)((int)u >> 31) | 0x80000000u;
            kv[i] = ((unsigned long long)u << 10) | (unsigned int)i;
        }
        __syncthreads();
        unsigned long long k0 = kv[tid], k1 = kv[tid + 256],
                           k2 = kv[tid + 512], k3 = kv[tid + 768];
        int r0 = 0, r1 = 0, r2 = 0, r3 = 0;
        int nkc = (Nb + 1) >> 1;               // odd-Nb tail key is INF: counts 0
#pragma unroll 4
        for (int c = 0; c < nkc; ++c) {
            ulonglong2 a = ((const ulonglong2*)kv)[c];
            r0 += (a.x < k0) + (a.y < k0);
            r1 += (a.x < k1) + (a.y < k1);
            r2 += (a.x < k2) + (a.y < k2);
            r3 += (a.x < k3) + (a.y < k3);
        }
        int rk[4] = {r0, r1, r2, r3};
#pragma unroll
        for (int t = 0; t < 4; ++t) {
            int i = tid + (t << 8);
            nml[i] = (yv[i] < INF && rk[t] >= nrem) ? 1.f : 0.f;
        }
        __syncthreads();
        // own 64-row slice: nm store + masked degree + coefficients (wave per row)
        int wave = tid >> 6, lane = tid & 63;
        for (int rd = 0; rd < 16; ++rd) {
            int i = (sub << 6) + (rd << 2) + wave;
            int gr = (b << 10) + i;
            if (i >= Nb) {                     // pad: next pool's float4 mask stage
                if (lane == 0) nmOut[gr] = 0.f;
                continue;
            }
            float m = nml[i];
            if (m == 0.f) {                    // dropped: only c1(=0)/scs(=0) read later
                if (lane == 0) {
                    nmOut[gr] = 0.f;
                    c1o[gr] = 0.f;
                    scso[gr] = 0.f;
                }
                continue;
            }
            int nn = cnt[gr];
            const unsigned short* ar = adj + (size_t)gr * CAP;
            float s = 0.f;
            if (lane < nn)      s  = nml[ar[lane]];
            if (lane + 64 < nn) s += nml[ar[lane + 64]];
            for (int sh = 32; sh; sh >>= 1) s += __shfl_xor(s, sh, 64);
            if (lane == 0) {
                nmOut[gr] = 1.f;
                float D = 1.0f / sqrtf(m * s + 1.0f + EPSV);
                c1o[gr] = m * D;               // == D bitwise (m==1)
                c2o[gr] = D * D;
                scso[gr] = tanhf(yv[i]) * m;   // yv==raw y here (m==1 -> not masked)
            }
        }
    }
}

// ---------------- final fc from the fused global-max buffer ----------------
__global__ __launch_bounds__(64) void k_fc(const float* __restrict__ gmax,
                                           const float* __restrict__ Wfc,
                                           const float* __restrict__ bfc,
                                           float* __restrict__ out) {
    __shared__ float gl[64];
    int b = blockIdx.x, lane = threadIdx.x;
    gl[lane] = gmax[(b << 6) + lane];
    __syncthreads();
    if (lane < NOUT) {
        float acc = bfc[lane];
        for (int k = 0; k < 64; ++k) acc += gl[k] * Wfc[k * NOUT + lane];
        out[b * NOUT + lane] = acc;
    }
}

extern "C" void kernel_launch(void* const* d_in, const int* in_sizes, int n_in,
                              void* d_out, int out_size, void* d_ws, size_t ws_size,
                              hipStream_t stream) {
    const float* x    = (const float*)d_in[0];
    const float* A    = (const float*)d_in[1];
    const float* mask = (const float*)d_in[2];
    const int*   Nn   = (const int*)d_in[3];
    const float* W0   = (const float*)d_in[4];
    const float* b0   = (const float*)d_in[5];
    const float* W1   = (const float*)d_in[6];
    const float* b1   = (const float*)d_in[7];
    const float* W2   = (const float*)d_in[8];
    const float* b2   = (const float*)d_in[9];
    const float* p0   = (const float*)d_in[10];
    const float* p1   = (const float*)d_in[11];
    const float* Wfc  = (const float*)d_in[12];
    const float* bfc  = (const float*)d_in[13];
    float* out = (float*)d_out;

    char* ws = (char*)d_ws;
    size_t off = 0;
    auto alloc = [&](size_t bytes) -> void* {
        void* p = ws + off;
        off = (off + bytes + 255) & ~(size_t)255;
        return p;
    };
    unsigned short* adj = (unsigned short*)alloc((size_t)BB * NN * CAP * 2);
    int*   cnt  = (int*)  alloc((size_t)BB * NN * 4);
    float* X    = (float*)alloc((size_t)BB * NN * 64 * 4);   // o1, then o2
    float* T    = (float*)alloc((size_t)BB * NN * 64 * 4);   // x@W0, o1@W1, o2@W2
    float* c1   = (float*)alloc((size_t)BB * NN * 4);
    float* c2   = (float*)alloc((size_t)BB * NN * 4);
    float* scs  = (float*)alloc((size_t)BB * NN * 4);        // tanh(y)*nm
    float* y    = (float*)alloc((size_t)BB * NN * 4);
    float* nm0  = (float*)alloc((size_t)BB * NN * 4);
    float* nm1  = (float*)alloc((size_t)BB * NN * 4);
    int*   nc0  = (int*)  alloc((size_t)BB * 4);
    int*   nc1  = (int*)  alloc((size_t)BB * 4);
    float* gmax = (float*)alloc((size_t)BB * 64 * 4);

    // 1) fused: CSR (8192) + x@W0 gemm (2048) + gmax relu(b2) seed (1 block)
    k_front<<<8192 + 2048 + 1, 256, 0, stream>>>(A, x, W0, Nn, b2, gmax,
                                                 adj, cnt, c1, c2, T);
    // 2) layer-1 SpMM + pool-1 score (pre-scaled path, R3-identical)
    k_spmm<0><<<2048, 256, 0, stream>>>(adj, cnt, c1, c2, T, b0, X, p0, y,
                                        nullptr, Nn, nullptr);
    // 3) pool-1 rank+deg+coeffs (512) + RAW o1@W1 gemm (2048) in ONE dispatch
    k_rankgemm<<<512 + 2048, 256, 0, stream>>>(y, mask, Nn, Nn, adj, cnt, X, W1,
                                               nm0, nc0, c1, c2, scs, T);
    // 4) layer-2 SpMM (deferred scale) + pool-2 score
    k_spmm<1><<<2048, 256, 0, stream>>>(adj, cnt, c1, c2, T, b1, X, p1, y,
                                        nullptr, Nn, scs);
    // 5) pool-2 rank+deg+coeffs (512) + RAW o2@W2 gemm (2048)
    k_rankgemm<<<512 + 2048, 256, 0, stream>>>(y, nm0, nc0, Nn, adj, cnt, X, W2,
                                               nm1, nc1, c1, c2, scs, T);
    // 6) layer-3 SpMM (deferred scale) + fused global max
    k_spmm<1><<<2048, 256, 0, stream>>>(adj, cnt, c1, c2, T, b2, nullptr, nullptr,
                                        nullptr, gmax, Nn, scs);
    // 7) fc from gmax
    k_fc<<<BB, 64, 0, stream>>>(gmax, Wfc, bfc, out);
}

// Round 8
// 353.544 us; speedup vs baseline: 1.1383x; 1.1383x over previous
//
#include <hip/hip_runtime.h>
#include <cstdint>
#include <cstddef>

#define BB 32
#define NN 1024
#define CIN 128
#define FF 64
#define NOUT 10
#define CAP 128
#define EPSV 1e-5f

// non-temporal float4 load: stream-once data (A, x, Xin) must not evict gather-hot rows.
typedef float vf4 __attribute__((ext_vector_type(4)));
__device__ __forceinline__ float4 ldnt(const float4* p) {
    vf4 v = __builtin_nontemporal_load((const vf4*)p);
    return make_float4(v.x, v.y, v.z, v.w);
}

// ---------------- fused front: [0,8192) CSR, [8192,10240) x@W0 gemm, [10240] seed ----
// R3-proven, unchanged.
__global__ __launch_bounds__(256) void k_front(const float* __restrict__ A,
                                               const float* __restrict__ x,
                                               const float* __restrict__ W0,
                                               const int* __restrict__ Nn,
                                               const float* __restrict__ b2f,
                                               float* __restrict__ gmax,
                                               unsigned short* __restrict__ adj,
                                               int* __restrict__ cnt,
                                               float* __restrict__ c1,
                                               float* __restrict__ c2,
                                               float* __restrict__ T) {
    __shared__ __align__(16) float Wl[64 * 64];    // 16 KB
    int tid = threadIdx.x;
    int wave = tid >> 6, lane = tid & 63;
    if (blockIdx.x >= 10240) {
        for (int i = tid; i < BB * 64; i += 256)
            gmax[i] = fmaxf(b2f[i & 63], 0.f);     // exact relu(b2) seed (dead rows)
        return;
    }
    if (blockIdx.x >= 8192) {
        int gid = blockIdx.x - 8192;        // gid%8 == b%8: XCD matches spmm
        int b = gid & 31;
        int cch = gid >> 5;
        if (cch * 16 >= Nn[b]) return;
        int row0 = (b << 10) + cch * 16;
        int rsub = lane >> 4, f0 = (lane & 15) * 4;
        int r = row0 + wave * 4 + rsub;
        const float4* xr = (const float4*)(x + (size_t)r * CIN);
        float4 acc = {0.f, 0.f, 0.f, 0.f};
#pragma unroll
        for (int kc = 0; kc < 2; ++kc) {
            if (kc) __syncthreads();
            for (int t = tid; t < 64 * 16; t += 256)
                ((float4*)Wl)[t] = ((const float4*)W0)[kc * 1024 + t];
            __syncthreads();
#pragma unroll 4
            for (int k4 = 0; k4 < 16; ++k4) {
                float4 xv = ldnt(xr + kc * 16 + k4);
                float4 w0 = *(const float4*)&Wl[(k4 * 4 + 0) * 64 + f0];
                float4 w1 = *(const float4*)&Wl[(k4 * 4 + 1) * 64 + f0];
                float4 w2 = *(const float4*)&Wl[(k4 * 4 + 2) * 64 + f0];
                float4 w3 = *(const float4*)&Wl[(k4 * 4 + 3) * 64 + f0];
                acc.x += xv.x * w0.x; acc.y += xv.x * w0.y; acc.z += xv.x * w0.z; acc.w += xv.x * w0.w;
                acc.x += xv.y * w1.x; acc.y += xv.y * w1.y; acc.z += xv.y * w1.z; acc.w += xv.y * w1.w;
                acc.x += xv.z * w2.x; acc.y += xv.z * w2.y; acc.z += xv.z * w2.z; acc.w += xv.z * w2.w;
                acc.x += xv.w * w3.x; acc.y += xv.w * w3.y; acc.z += xv.w * w3.z; acc.w += xv.w * w3.w;
            }
        }
        *(float4*)&T[(size_t)r * 64 + f0] = acc;
    } else {
        int r = blockIdx.x * 4 + wave;
        int b = r >> 10;
        int Nb = Nn[b];
        int rl = r & 1023;
        if (rl >= Nb) {
            if (lane == 0) {
                cnt[r] = 0;
                float D = 1.0f / sqrtf(1.0f + EPSV);
                c1[r] = D;
                c2[r] = D * D;
            }
            return;
        }
        unsigned short* adjs = ((unsigned short*)Wl) + wave * CAP;
        const float4* Arow = (const float4*)(A + (size_t)r * NN);
        int nch = (Nb + 255) >> 8;
        float4 z4 = {0.f, 0.f, 0.f, 0.f};
        float4 v0 = ldnt(Arow + lane);
        float4 v1 = ldnt(Arow + 64 + lane);
        float4 v2 = (nch > 2) ? ldnt(Arow + 128 + lane) : z4;
        float4 v3 = (nch > 3) ? ldnt(Arow + 192 + lane) : z4;
        int c = 0;
        unsigned long long lt = (lane == 0) ? 0ULL : ((1ULL << lane) - 1ULL);
        float4 vv[4] = {v0, v1, v2, v3};
#pragma unroll
        for (int it = 0; it < 4; ++it) {
            float4 v = vv[it];
            int j0 = it * 256 + lane * 4;
            unsigned long long m0 = __ballot(v.x != 0.f);
            unsigned long long m1 = __ballot(v.y != 0.f);
            unsigned long long m2 = __ballot(v.z != 0.f);
            unsigned long long m3 = __ballot(v.w != 0.f);
            int before = __popcll(m0 & lt) + __popcll(m1 & lt) +
                         __popcll(m2 & lt) + __popcll(m3 & lt);
            int p = c + before;
            if (v.x != 0.f) { if (p < CAP) adjs[p] = (unsigned short)(j0 + 0); ++p; }
            if (v.y != 0.f) { if (p < CAP) adjs[p] = (unsigned short)(j0 + 1); ++p; }
            if (v.z != 0.f) { if (p < CAP) adjs[p] = (unsigned short)(j0 + 2); ++p; }
            if (v.w != 0.f) { if (p < CAP) adjs[p] = (unsigned short)(j0 + 3); ++p; }
            c += __popcll(m0) + __popcll(m1) + __popcll(m2) + __popcll(m3);
        }
        int cc = (c > CAP) ? CAP : c;
        uint32_t* dst = (uint32_t*)(adj + (size_t)r * CAP);
        if (lane * 2 < cc) dst[lane] = ((const uint32_t*)adjs)[lane];
        if (lane == 0) {
            cnt[r] = cc;
            float D = 1.0f / sqrtf((float)c + 1.0f + EPSV);
            c1[r] = D;
            c2[r] = D * D;
        }
    }
}

// ---------------- fused mid: [0,8192) = deg, [8192,10240) = gemm64 (scaled) --------------
// byte-identical to R3 (proven).
__global__ __launch_bounds__(256) void k_mid(const unsigned short* __restrict__ adj,
                                             const int* __restrict__ cnt,
                                             const float* __restrict__ nm,
                                             float* __restrict__ c1, float* __restrict__ c2,
                                             const float* __restrict__ Xin,
                                             const float* __restrict__ W,
                                             const float* __restrict__ y,
                                             float* __restrict__ T,
                                             const int* __restrict__ Nn) {
    __shared__ __align__(16) float Wl[64 * 64];    // 16 KB
    int tid = threadIdx.x;
    if (blockIdx.x >= 8192) {
        int gid = blockIdx.x - 8192;
        int b = gid & 31;
        int cch = gid >> 5;
        if (cch * 16 >= Nn[b]) return;
        int row0 = (b << 10) + cch * 16;
        for (int t = tid; t < 64 * 16; t += 256)
            ((float4*)Wl)[t] = ((const float4*)W)[t];
        __syncthreads();
        int wave = tid >> 6, lane = tid & 63;
        int rsub = lane >> 4, f0 = (lane & 15) * 4;
        int r = row0 + wave * 4 + rsub;
        float sc = tanhf(y[r]) * nm[r];
        const float4* xr = (const float4*)(Xin + (size_t)r * 64);
        float4 acc = {0.f, 0.f, 0.f, 0.f};
#pragma unroll 4
        for (int k4 = 0; k4 < 16; ++k4) {
            float4 xv = ldnt(xr + k4);
            float4 w0 = *(const float4*)&Wl[(k4 * 4 + 0) * 64 + f0];
            float4 w1 = *(const float4*)&Wl[(k4 * 4 + 1) * 64 + f0];
            float4 w2 = *(const float4*)&Wl[(k4 * 4 + 2) * 64 + f0];
            float4 w3 = *(const float4*)&Wl[(k4 * 4 + 3) * 64 + f0];
            acc.x += xv.x * w0.x; acc.y += xv.x * w0.y; acc.z += xv.x * w0.z; acc.w += xv.x * w0.w;
            acc.x += xv.y * w1.x; acc.y += xv.y * w1.y; acc.z += xv.y * w1.z; acc.w += xv.y * w1.w;
            acc.x += xv.z * w2.x; acc.y += xv.z * w2.y; acc.z += xv.z * w2.z; acc.w += xv.z * w2.w;
            acc.x += xv.w * w3.x; acc.y += xv.w * w3.y; acc.z += xv.w * w3.z; acc.w += xv.w * w3.w;
        }
        acc.x *= sc; acc.y *= sc; acc.z *= sc; acc.w *= sc;
        *(float4*)&T[(size_t)r * 64 + f0] = acc;
    } else {
        int wave = tid >> 6, lane = tid & 63;
        int r = blockIdx.x * 4 + wave;
        int b = r >> 10;
        if ((r & 1023) >= Nn[b]) return;
        float m = nm[r];
        if (m == 0.f) {
            if (lane == 0) c1[r] = 0.f;
            return;
        }
        const unsigned short* arow = adj + (size_t)r * CAP;
        const float* nmb = nm + (b << 10);
        int n = cnt[r];
        float s = 0.f;
        if (lane < n)      s  = nmb[arow[lane]];
        if (lane + 64 < n) s += nmb[arow[lane + 64]];
        for (int sh = 32; sh; sh >>= 1) s += __shfl_xor(s, sh, 64);
        if (lane == 0) {
            float D = 1.0f / sqrtf(m * s + 1.0f + EPSV);
            c1[r] = m * D;
            c2[r] = D * D;
        }
    }
}

// ---------------- SpMM: R8 = 512 threads, 8 waves x 2 rows (anti-skew) ----------------
// Per-row gather loop byte-identical to R3 (same ascending-t order, same acc split).
// Same 2048 blocks / 16 rows / c1s amortization; block critical path halves
// (sum(deg)/8 waves instead of /4) -> straggler-tail (27% time-avg occupancy in R5
// profile) shrinks. 4 blocks/CU still saturates 32 waves/CU.
__global__ __launch_bounds__(512) void k_spmm(const unsigned short* __restrict__ adj,
                                              const int* __restrict__ cnt,
                                              const float* __restrict__ c1,
                                              const float* __restrict__ c2,
                                              const float* __restrict__ T,
                                              const float* __restrict__ bias,
                                              float* __restrict__ X,
                                              const float* __restrict__ p,
                                              float* __restrict__ y,
                                              float* __restrict__ gmax,
                                              const int* __restrict__ Nn) {
    __shared__ __align__(16) float c1s[NN];
    __shared__ float red[8][64];
    int b   = blockIdx.x & 31;            // graph
    int cch = blockIdx.x >> 5;            // chunk in [0,64)
    int Nb = Nn[b];
    if (cch * 16 >= Nb) return;
    int tid = threadIdx.x;
    int n4 = (Nb + 3) >> 2;               // <=256: staged by tids 0..255
    if (tid < n4) ((float4*)c1s)[tid] = ((const float4*)(c1 + (b << 10)))[tid];
    __syncthreads();
    int wave = tid >> 6, lane = tid & 63;
    int r0 = (b << 10) + cch * 16 + wave * 2;     // 2 rows per wave
    const float* Tb = T + ((size_t)(b << 10) << 6);
    float bv = bias[lane];
    float pv = 0.f, ppinv = 0.f;
    if (p != nullptr) {
        pv = p[lane];
        float pp = pv * pv;
        for (int s = 32; s; s >>= 1) pp += __shfl_xor(pp, s, 64);
        ppinv = 1.0f / sqrtf(pp);
    }
    float vmax = 0.f;
#pragma unroll
    for (int rr = 0; rr < 2; ++rr) {
        int r = r0 + rr;
        int rl = r & 1023;
        if (rl >= Nb) break;              // rows ascending within wave
        if (c1s[rl] == 0.f) continue;     // pool-dropped (layers 2/3); layer-1 c1>0
        const unsigned short* arow = adj + (size_t)r * CAP;
        int n = cnt[r];
        float acc0 = 0.f, acc1 = 0.f, acc2 = 0.f, acc3 = 0.f;
        int t = 0;
        for (; t + 4 <= n; t += 4) {
            ushort4 j4 = *(const ushort4*)(arow + t);
            acc0 += c1s[j4.x] * Tb[((int)j4.x << 6) + lane];
            acc1 += c1s[j4.y] * Tb[((int)j4.y << 6) + lane];
            acc2 += c1s[j4.z] * Tb[((int)j4.z << 6) + lane];
            acc3 += c1s[j4.w] * Tb[((int)j4.w << 6) + lane];
        }
        for (; t < n; ++t) {
            int j = arow[t];
            acc0 += c1s[j] * Tb[(j << 6) + lane];
        }
        float acc = (acc0 + acc1) + (acc2 + acc3);
        float o = c1s[rl] * acc + c2[r] * T[((size_t)r << 6) + lane] + bv;
        o = fmaxf(o, 0.f);
        if (X != nullptr) X[((size_t)r << 6) + lane] = o;
        if (p != nullptr) {
            float a = o * pv;
            for (int s = 32; s; s >>= 1) a += __shfl_xor(a, s, 64);
            if (lane == 0) y[r] = a * ppinv;
        }
        vmax = fmaxf(vmax, o);
    }
    if (gmax != nullptr) {
        red[wave][lane] = vmax;
        __syncthreads();
        if (wave == 0) {
            float m = fmaxf(fmaxf(fmaxf(red[0][lane], red[1][lane]),
                                  fmaxf(red[2][lane], red[3][lane])),
                            fmaxf(fmaxf(red[4][lane], red[5][lane]),
                                  fmaxf(red[6][lane], red[7][lane])));
            atomicMax((int*)&gmax[(b << 6) + lane], __float_as_int(m));
        }
    }
}

// ---------------- pool ranking: stable-argsort semantics, 16 blocks/graph (R3) -----------
__global__ __launch_bounds__(256) void k_rank(const float* __restrict__ y,
                                              const float* __restrict__ maskSrc,
                                              const int* __restrict__ nsrc,
                                              const int* __restrict__ nbound,
                                              float* __restrict__ nmOut,
                                              int* __restrict__ ncur) {
    __shared__ __align__(16) float yv[NN];
    int b = blockIdx.x >> 4;
    int sub = blockIdx.x & 15;
    int tid = threadIdx.x;
    const float INF = __builtin_inff();
    int Nb = nbound[b];
    if ((sub << 6) >= Nb) return;
    {
        float4 v;
        if (tid * 4 < Nb) {
            v = ((const float4*)(y + (b << 10)))[tid];
            float4 m = ((const float4*)(maskSrc + (b << 10)))[tid];
            v.x = (m.x > 0.f) ? v.x : INF;
            v.y = (m.y > 0.f) ? v.y : INF;
            v.z = (m.z > 0.f) ? v.z : INF;
            v.w = (m.w > 0.f) ? v.w : INF;
        } else {
            v.x = INF; v.y = INF; v.z = INF; v.w = INF;
        }
        ((float4*)yv)[tid] = v;
    }
    int n = nsrc[b];
    const float RM = (float)(1.0 - 0.8);
    int nrem = (int)((float)n * RM);
    if (sub == 0 && tid == 0) ncur[b] = n - nrem;
    __syncthreads();
    int i = (sub << 6) + (tid >> 2);
    int q = tid & 3;
    float yi = yv[i];
    int rank = 0;
    if (yi < INF) {
        const float4* jbase = (const float4*)yv + (q << 6);
        int j0 = q << 8;
        int tend = (Nb - j0 + 3) >> 2;
        if (tend > 64) tend = 64;
#pragma unroll 8
        for (int t = 0; t < tend; ++t) {
            float4 a = jbase[t];
            int j = j0 + t * 4;
            rank += (a.x < yi || (a.x == yi && j     < i)) ? 1 : 0;
            rank += (a.y < yi || (a.y == yi && j + 1 < i)) ? 1 : 0;
            rank += (a.z < yi || (a.z == yi && j + 2 < i)) ? 1 : 0;
            rank += (a.w < yi || (a.w == yi && j + 3 < i)) ? 1 : 0;
        }
    }
    rank += __shfl_xor(rank, 1, 64);
    rank += __shfl_xor(rank, 2, 64);
    if (q == 0) {
        float nmv = (yi < INF && rank >= nrem) ? 1.f : 0.f;
        nmOut[(b << 10) + i] = nmv;
    }
}

// ---------------- final fc from the fused global-max buffer ----------------
__global__ __launch_bounds__(64) void k_fc(const float* __restrict__ gmax,
                                           const float* __restrict__ Wfc,
                                           const float* __restrict__ bfc,
                                           float* __restrict__ out) {
    __shared__ float gl[64];
    int b = blockIdx.x, lane = threadIdx.x;
    gl[lane] = gmax[(b << 6) + lane];
    __syncthreads();
    if (lane < NOUT) {
        float acc = bfc[lane];
        for (int k = 0; k < 64; ++k) acc += gl[k] * Wfc[k * NOUT + lane];
        out[b * NOUT + lane] = acc;
    }
}

extern "C" void kernel_launch(void* const* d_in, const int* in_sizes, int n_in,
                              void* d_out, int out_size, void* d_ws, size_t ws_size,
                              hipStream_t stream) {
    const float* x    = (const float*)d_in[0];
    const float* A    = (const float*)d_in[1];
    const float* mask = (const float*)d_in[2];
    const int*   Nn   = (const int*)d_in[3];
    const float* W0   = (const float*)d_in[4];
    const float* b0   = (const float*)d_in[5];
    const float* W1   = (const float*)d_in[6];
    const float* b1   = (const float*)d_in[7];
    const float* W2   = (const float*)d_in[8];
    const float* b2   = (const float*)d_in[9];
    const float* p0   = (const float*)d_in[10];
    const float* p1   = (const float*)d_in[11];
    const float* Wfc  = (const float*)d_in[12];
    const float* bfc  = (const float*)d_in[13];
    float* out = (float*)d_out;

    char* ws = (char*)d_ws;
    size_t off = 0;
    auto alloc = [&](size_t bytes) -> void* {
        void* p = ws + off;
        off = (off + bytes + 255) & ~(size_t)255;
        return p;
    };
    unsigned short* adj = (unsigned short*)alloc((size_t)BB * NN * CAP * 2);
    int*   cnt  = (int*)  alloc((size_t)BB * NN * 4);
    float* X    = (float*)alloc((size_t)BB * NN * 64 * 4);
    float* T    = (float*)alloc((size_t)BB * NN * 64 * 4);
    float* c1   = (float*)alloc((size_t)BB * NN * 4);
    float* c2   = (float*)alloc((size_t)BB * NN * 4);
    float* y    = (float*)alloc((size_t)BB * NN * 4);
    float* nm0  = (float*)alloc((size_t)BB * NN * 4);
    float* nm1  = (float*)alloc((size_t)BB * NN * 4);
    int*   nc0  = (int*)  alloc((size_t)BB * 4);
    int*   nc1  = (int*)  alloc((size_t)BB * 4);
    float* gmax = (float*)alloc((size_t)BB * 64 * 4);

    // 1) fused: CSR (8192) + x@W0 gemm (2048) + gmax relu(b2) seed (1 block)
    k_front<<<8192 + 2048 + 1, 256, 0, stream>>>(A, x, W0, Nn, b2, gmax,
                                                 adj, cnt, c1, c2, T);
    // 2) layer-1 SpMM + pool-1 score
    k_spmm<<<2048, 512, 0, stream>>>(adj, cnt, c1, c2, T, b0, X, p0, y, nullptr, Nn);
    // pool 1
    k_rank<<<BB * 16, 256, 0, stream>>>(y, mask, Nn, Nn, nm0, nc0);
    // 3) layer 2: fused deg (first) + gemm64
    k_mid<<<8192 + 2048, 256, 0, stream>>>(adj, cnt, nm0, c1, c2, X, W1, y, T, Nn);
    k_spmm<<<2048, 512, 0, stream>>>(adj, cnt, c1, c2, T, b1, X, p1, y, nullptr, Nn);
    // pool 2
    k_rank<<<BB * 16, 256, 0, stream>>>(y, nm0, nc0, Nn, nm1, nc1);
    // 4) layer 3: fused deg (first) + gemm64; spmm fuses global max (no X write)
    k_mid<<<8192 + 2048, 256, 0, stream>>>(adj, cnt, nm1, c1, c2, X, W2, y, T, Nn);
    k_spmm<<<2048, 512, 0, stream>>>(adj, cnt, c1, c2, T, b2, nullptr, nullptr, nullptr,
                                     gmax, Nn);
    // 5) fc from gmax
    k_fc<<<BB, 64, 0, stream>>>(gmax, Wfc, bfc, out);
}